// Round 6
// baseline (560.623 us; speedup 1.0000x reference)
//
#include <hip/hip_runtime.h>

// FragAttention: masked prefix-sum along s.
//   x: (S, B, D) f32, src_mask: (B, S) int (True=pad)
//   out: (B, G, 2D) f32, G = S-1
//   left[b,g,d]  = sum_{s<=g} x[s,b,d]*valid[b,s]
//   right[b,g,d] = total[b,d] - left[b,g,d]
//
// R6 = R5 resubmit (R5 never ran: GPUAcquisitionTimeout, broker at capacity).
// MEASUREMENT ROUND. The real kernel (R1 config, best so far) runs first for
// correctness. Then a probe = the IDENTICAL kernel body repeated 4x, writing
// into d_ws (guarded: only if ws_size >= 266MB). At 4 reps the probe
// dispatch is >200us -> lands in rocprof's top-5 table with its own dur_us /
// FETCH / WRITE / hbm_gbps / VALUBusy / Occupancy. This resolves the
// H-vs-kernel decomposition R0-R4 could not: probe/4 ~= true kernel time
// (rep1 cold-x, reps 2-4 L3-warm-x give the warm bound too).
#define SS 128
#define BB 512
#define DD 512
#define GG 127
#define CS 8     // s-values per thread
#define NC 16    // chunks
#define NCOL 32  // float4 columns per block (= 128 floats of d)
#define REPS 4   // probe repetitions

typedef float f4 __attribute__((ext_vector_type(4)));

// ---------------- real kernel: exact R1 config ----------------------------
__global__ __launch_bounds__(512, 6) void frag_prefix_kernel(
    const float* __restrict__ x, const int* __restrict__ mask,
    float* __restrict__ out) {
  const int tid = threadIdx.x;
  const int b = blockIdx.x >> 2;
  const int dblk = (blockIdx.x & 3) << 7;  // 0,128,256,384 (floats)
  const int col = tid & (NCOL - 1);        // float4 column within block
  const int j = tid >> 5;                  // s-chunk id, 0..15

  __shared__ float valid[SS];
  __shared__ f4 part[NC][NCOL];

  if (tid < SS) valid[tid] = mask[b * SS + tid] ? 0.0f : 1.0f;
  __syncthreads();

  const size_t sstride = (size_t)BB * DD / 4;
  const f4* xq = (const f4*)x + (size_t)(j * CS) * sstride +
                 ((size_t)b * DD + dblk) / 4 + col;

  f4 v[CS];
#pragma unroll
  for (int i = 0; i < CS; ++i) {
    f4 t = __builtin_nontemporal_load(xq + (size_t)i * sstride);
    v[i] = t * valid[j * CS + i];
  }

  f4 psum = v[0];
#pragma unroll
  for (int i = 1; i < CS; ++i) psum += v[i];
  part[j][col] = psum;
  __syncthreads();

  f4 offset = {0.f, 0.f, 0.f, 0.f};
  f4 total = {0.f, 0.f, 0.f, 0.f};
#pragma unroll
  for (int jj = 0; jj < NC; ++jj) {
    f4 p = part[jj][col];
    total += p;
    if (jj < j) offset += p;
  }

  f4* op = (f4*)out + ((size_t)b * GG * 2 * DD + dblk) / 4 + col;
  f4 run = offset;
#pragma unroll
  for (int i = 0; i < CS; ++i) {
    run += v[i];
    const int g = j * CS + i;
    if (g < GG) {
      __builtin_nontemporal_store(run, op + (size_t)g * (2 * DD / 4));
      f4 r = total - run;
      __builtin_nontemporal_store(r, op + (size_t)g * (2 * DD / 4) + DD / 4);
    }
  }
}

// ---------------- probe: identical body x REPS, writes to ws --------------
__global__ __launch_bounds__(512, 6) void probe_kernel(
    const float* __restrict__ x, const int* __restrict__ mask,
    float* __restrict__ out) {
  const int tid = threadIdx.x;
  const int b = blockIdx.x >> 2;
  const int dblk = (blockIdx.x & 3) << 7;
  const int col = tid & (NCOL - 1);
  const int j = tid >> 5;

  __shared__ float valid[SS];
  __shared__ f4 part[NC][NCOL];

  if (tid < SS) valid[tid] = mask[b * SS + tid] ? 0.0f : 1.0f;
  __syncthreads();

  const size_t sstride = (size_t)BB * DD / 4;
  const f4* xq = (const f4*)x + (size_t)(j * CS) * sstride +
                 ((size_t)b * DD + dblk) / 4 + col;
  f4* op = (f4*)out + ((size_t)b * GG * 2 * DD + dblk) / 4 + col;

  for (int rep = 0; rep < REPS; ++rep) {
    f4 v[CS];
#pragma unroll
    for (int i = 0; i < CS; ++i) {
      f4 t = __builtin_nontemporal_load(xq + (size_t)i * sstride);
      v[i] = t * valid[j * CS + i];
    }

    f4 psum = v[0];
#pragma unroll
    for (int i = 1; i < CS; ++i) psum += v[i];
    __syncthreads();  // prev rep's part[] readers done
    part[j][col] = psum;
    __syncthreads();

    f4 offset = {0.f, 0.f, 0.f, 0.f};
    f4 total = {0.f, 0.f, 0.f, 0.f};
#pragma unroll
    for (int jj = 0; jj < NC; ++jj) {
      f4 p = part[jj][col];
      total += p;
      if (jj < j) offset += p;
    }

    f4 run = offset;
#pragma unroll
    for (int i = 0; i < CS; ++i) {
      run += v[i];
      const int g = j * CS + i;
      if (g < GG) {
        __builtin_nontemporal_store(run, op + (size_t)g * (2 * DD / 4));
        f4 r = total - run;
        __builtin_nontemporal_store(r, op + (size_t)g * (2 * DD / 4) + DD / 4);
      }
    }
  }
}

extern "C" void kernel_launch(void* const* d_in, const int* in_sizes, int n_in,
                              void* d_out, int out_size, void* d_ws, size_t ws_size,
                              hipStream_t stream) {
  const float* x = (const float*)d_in[0];
  const int* mask = (const int*)d_in[1];
  float* out = (float*)d_out;
  // Real kernel: 4 blocks per b (128 floats of d each) -> 2048 x 512.
  frag_prefix_kernel<<<dim3(BB * 4), dim3(512), 0, stream>>>(x, mask, out);
  // Probe into workspace (same footprint as out), only if ws is big enough.
  const size_t probe_bytes = (size_t)BB * GG * 2 * DD * sizeof(float);
  if (d_ws != nullptr && ws_size >= probe_bytes) {
    probe_kernel<<<dim3(BB * 4), dim3(512), 0, stream>>>(
        x, mask, (float*)d_ws);
  }
}